// Round 3
// baseline (483.659 us; speedup 1.0000x reference)
//
#include <hip/hip_runtime.h>
#include <hip/hip_bf16.h>
#include <stdint.h>

typedef unsigned short u16;
typedef __bf16 bf16x8 __attribute__((ext_vector_type(8)));
typedef float  f32x4  __attribute__((ext_vector_type(4)));
typedef u16    u16x8  __attribute__((ext_vector_type(8)));

__device__ __forceinline__ float bf2f(u16 u) {
    return __uint_as_float(((unsigned)u) << 16);
}
__device__ __forceinline__ u16 f2bf(float f) {   // round-to-nearest-even
    unsigned u = __float_as_uint(f);
    u += 0x7fffu + ((u >> 16) & 1u);
    return (u16)(u >> 16);
}
__device__ __forceinline__ u16x8 maxu16(u16x8 a, u16x8 b) {
    u16x8 r;
    #pragma unroll
    for (int e = 0; e < 8; ++e) r[e] = a[e] > b[e] ? a[e] : b[e];
    return r;
}
__device__ __forceinline__ f32x4 maxf4(f32x4 a, f32x4 b) {
    f32x4 r;
    #pragma unroll
    for (int e = 0; e < 4; ++e) r[e] = fmaxf(a[e], b[e]);
    return r;
}

#define MFMA16(a, b, c) __builtin_amdgcn_mfma_f32_16x16x32_bf16(a, b, c, 0, 0, 0)

// Static device buffers — no d_ws dependency.
__device__ u16   h2g_buf[262144 * 64];   // h2 [N][64] bf16 (33.5 MB)
__device__ u16   gm_buf [262144 * 64];   // neighbor-max [N][64] bf16 (33.5 MB)
__device__ u16   w3b[64 * 64];           // weights pre-converted to bf16
__device__ u16   w4b[128 * 64];
__device__ u16   w5b[1024 * 192];
__device__ float g_buf[1024];            // global column max (>= 0)
__device__ float f1_buf[512];
__device__ float f2_buf[256];

// ---------------------------------------------------------------------------
__global__ void k0_zero() { g_buf[threadIdx.x] = 0.f; }

__global__ void kcvt(const float* __restrict__ w3f, const float* __restrict__ w4f,
                     const float* __restrict__ w5f)
{
    int i = blockIdx.x * 256 + threadIdx.x;
    if (i < 4096)        w3b[i]         = f2bf(w3f[i]);
    else if (i < 12288)  w4b[i - 4096]  = f2bf(w4f[i - 4096]);
    else                 w5b[i - 12288] = f2bf(w5f[i - 12288]);
}

// ---------------------------------------------------------------------------
// k1: mlp1+mlp2 for 64 points/block (f32 in -> bf16). Writes h2g_buf.
// ---------------------------------------------------------------------------
__global__ __launch_bounds__(256) void k1_mlp(
    const float* __restrict__ xf, const float* __restrict__ w1f,
    const float* __restrict__ w2f)
{
    __shared__ __align__(16) u16 sw1[64 * 4];
    __shared__ __align__(16) u16 sx [64 * 4];
    __shared__ __align__(16) u16 sw2[64 * 72];
    __shared__ __align__(16) u16 shA[64 * 72];
    __shared__ __align__(16) u16 sh2[64 * 72];

    const int tid = threadIdx.x;
    const int p0  = blockIdx.x * 64;

    for (int i = tid; i < 64 * 64; i += 256)
        sw2[(i >> 6) * 72 + (i & 63)] = f2bf(w2f[i]);
    if (tid < 192) {
        sw1[(tid / 3) * 4 + tid % 3] = f2bf(w1f[tid]);
        sx [(tid / 3) * 4 + tid % 3] = f2bf(xf[p0 * 3 + tid]);
    }
    __syncthreads();

    {   // L1 via VALU (K=3)
        int m = tid & 63, ng = tid >> 6;
        float x0 = bf2f(sx[m * 4]), x1 = bf2f(sx[m * 4 + 1]), x2 = bf2f(sx[m * 4 + 2]);
        #pragma unroll
        for (int j = 0; j < 16; ++j) {
            int n = ng * 16 + j;
            float s = x0 * bf2f(sw1[n * 4]) + x1 * bf2f(sw1[n * 4 + 1]) + x2 * bf2f(sw1[n * 4 + 2]);
            shA[m * 72 + n] = f2bf(fmaxf(s, 0.f));
        }
    }
    __syncthreads();

    const int lane = tid & 63, w = tid >> 6, q = lane >> 4, l15 = lane & 15;
    const int mrow = 16 * w;

    f32x4 acc2[4];
    #pragma unroll
    for (int nt = 0; nt < 4; ++nt) acc2[nt] = (f32x4){0.f, 0.f, 0.f, 0.f};
    #pragma unroll
    for (int s = 0; s < 2; ++s) {
        bf16x8 a = *(const bf16x8*)&shA[(mrow + l15) * 72 + s * 32 + q * 8];
        #pragma unroll
        for (int nt = 0; nt < 4; ++nt) {
            bf16x8 b = *(const bf16x8*)&sw2[(nt * 16 + l15) * 72 + s * 32 + q * 8];
            acc2[nt] = MFMA16(a, b, acc2[nt]);
        }
    }
    #pragma unroll
    for (int nt = 0; nt < 4; ++nt)
        #pragma unroll
        for (int r = 0; r < 4; ++r) {
            int m = mrow + q * 4 + r;
            sh2[m * 72 + nt * 16 + l15] = f2bf(fmaxf(acc2[nt][r], 0.f));
        }
    __syncthreads();

    {
        int row = tid >> 2, c = (tid & 3) * 16;
        *(u16x8*)&h2g_buf[(size_t)p0 * 64 + tid * 16]     = *(const u16x8*)&sh2[row * 72 + c];
        *(u16x8*)&h2g_buf[(size_t)p0 * 64 + tid * 16 + 8] = *(const u16x8*)&sh2[row * 72 + c + 8];
    }
}

// ---------------------------------------------------------------------------
// k2_pool: 8 threads per point (thread owns a 16B channel chunk). 16
//   INDEPENDENT gather loads issued back-to-back per thread, local packed-u16
//   max (valid: post-relu bf16 >= 0), direct 16B store.
// ---------------------------------------------------------------------------
__global__ __launch_bounds__(256) void k2_pool(const int* __restrict__ idx)
{
    const size_t gt = (size_t)blockIdx.x * 256 + threadIdx.x;
    const size_t p  = gt >> 3;              // point
    const int    c  = (threadIdx.x & 7) * 8; // channel chunk

    u16x8 v[16];
    #pragma unroll
    for (int k = 0; k < 16; ++k) {
        int j = idx[p * 16 + k];
        v[k] = *(const u16x8*)&h2g_buf[(size_t)j * 64 + c];
    }
    u16x8 m = v[0];
    #pragma unroll
    for (int k = 1; k < 16; ++k) m = maxu16(m, v[k]);
    *(u16x8*)&gm_buf[p * 64 + c] = m;
}

// ---------------------------------------------------------------------------
// k3 v4: PERSISTENT blocks, B (w5) resident in VGPRs.
//   Identical structure to v3; the ONE change is __launch_bounds__(512, 1).
//   HIP launch_bounds arg2 is CUDA-semantics MIN BLOCKS PER CU: v3's (512,2)
//   meant 16 waves/CU -> 4 waves/SIMD -> VGPR cap 128, which spilled the
//   ~230 live regs (b5=96, acc=64, rmax=16, a=16, prefetch=16, addr~20) to
//   scratch (rocprof: WRITE_SIZE 163MB of scratch writeback, MfmaUtil 20%).
//   (512,1) -> cap 256 VGPR, no spill.  LDS 120KB already limits residency
//   to 1 block/CU (8 waves), so nothing is lost.
//   Grid = 256 blocks x 512 threads (8 waves: 2m x 4n).  Block owns a 256-col
//   group of w5 (cg = bid>>6) and loops over 32 row-tiles (brow = bid&63).
//   The 4 blocks sharing a row range have equal bid%8 -> same XCD -> A
//   fetched once per XCD L2 (FETCH 46MB confirms).
//   Per tile: prefetch A(t+1) to regs -> P4 (h3, wave-local rows) -> P5 (h4,
//   wave-local) -> barrier -> mlp5 (6 x [4 ds_read + 16 MFMA], B from regs)
//   -> write A(t+1) -> barrier.  Column-max in regs; atomics at block end.
// ---------------------------------------------------------------------------
__global__ __launch_bounds__(512, 1) void k3_fused(int* __restrict__ gout)
{
    __shared__ __align__(16) u16 lds[61440];      // 120 KB
    u16* sA0 = lds;                               // [128][192] swizzled
    u16* sA1 = lds + 24576;
    u16* sw3 = lds + 49152;                       // [64][64] swizzled
    u16* sw4 = lds + 53248;                       // [128][64] swizzled

    const int tid  = threadIdx.x;
    const int lane = tid & 63, w = tid >> 6, q = lane >> 4, l15 = lane & 15;
    const int mw   = w & 1, nw = w >> 1;
    const int cg   = blockIdx.x >> 6;             // column group 0..3
    const int brow = blockIdx.x & 63;             // row chunk   0..63
    const int bcol0 = cg * 256 + nw * 64;

    // ---- stage w3/w4 into LDS (once) ----
    {
        int r = tid >> 3, js = tid & 7;
        *(u16x8*)&sw3[r * 64 + ((js ^ r) & 7) * 8] = *(const u16x8*)&w3b[r * 64 + js * 8];
        #pragma unroll
        for (int c = 0; c < 2; ++c) {
            int i = c * 512 + tid, r4 = i >> 3, j4 = i & 7;
            *(u16x8*)&sw4[r4 * 64 + ((j4 ^ r4) & 7) * 8] = *(const u16x8*)&w4b[r4 * 64 + j4 * 8];
        }
    }

    // ---- B (w5) fragments resident in VGPRs: 24 x bf16x8 = 96 VGPR ----
    bf16x8 b5[6][4];
    #pragma unroll
    for (int s = 0; s < 6; ++s)
        #pragma unroll
        for (int nt = 0; nt < 4; ++nt)
            b5[s][nt] = *(const bf16x8*)&w5b[(size_t)(bcol0 + nt * 16 + l15) * 192 + s * 32 + q * 8];

    // ---- stage tile 0 ----
    {
        size_t R0 = (size_t)brow * 32 * 128;
        #pragma unroll
        for (int c = 0; c < 2; ++c) {
            int i = c * 512 + tid, r = i >> 3, js = i & 7;
            *(u16x8*)&sA0[r * 192 + ((js ^ r) & 7) * 8] =
                *(const u16x8*)&gm_buf[(R0 + r) * 64 + js * 8];
            *(u16x8*)&sA0[r * 192 + (8 | ((js ^ r) & 7)) * 8] =
                *(const u16x8*)&h2g_buf[(R0 + r) * 64 + js * 8];
        }
    }
    __syncthreads();

    f32x4 rmax[4];
    #pragma unroll
    for (int nt = 0; nt < 4; ++nt) rmax[nt] = (f32x4){0.f, 0.f, 0.f, 0.f};

    u16* pc = sA0;
    u16* pn = sA1;

    #pragma unroll 1
    for (int t = 0; t < 32; ++t) {
        // ---- prefetch A(t+1) into regs (latency hidden under compute) ----
        u16x8 vg[2], vh[2];
        if (t < 31) {
            size_t R1 = (size_t)(brow * 32 + t + 1) * 128;
            #pragma unroll
            for (int c = 0; c < 2; ++c) {
                int i = c * 512 + tid, r = i >> 3, js = i & 7;
                vg[c] = *(const u16x8*)&gm_buf[(R1 + r) * 64 + js * 8];
                vh[c] = *(const u16x8*)&h2g_buf[(R1 + r) * 64 + js * 8];
            }
        }

        // ---- P4: h3 = relu(h2 @ w3^T) -> cols 128..191 (wave-local rows) ----
        {
            f32x4 a3[4];
            #pragma unroll
            for (int nt = 0; nt < 4; ++nt) a3[nt] = (f32x4){0.f, 0.f, 0.f, 0.f};
            #pragma unroll
            for (int ss = 0; ss < 2; ++ss) {
                int js = ss * 4 + q, r = w * 16 + l15;
                bf16x8 a = *(const bf16x8*)&pc[r * 192 + (8 | ((js ^ r) & 7)) * 8];
                #pragma unroll
                for (int nt = 0; nt < 4; ++nt) {
                    int rw = nt * 16 + l15;
                    bf16x8 b = *(const bf16x8*)&sw3[rw * 64 + ((js ^ rw) & 7) * 8];
                    a3[nt] = MFMA16(a, b, a3[nt]);
                }
            }
            #pragma unroll
            for (int nt = 0; nt < 4; ++nt)
                #pragma unroll
                for (int r = 0; r < 4; ++r) {
                    int m = w * 16 + q * 4 + r;
                    int n = nt * 16 + l15;
                    pc[m * 192 + (16 | (((n >> 3) ^ m) & 7)) * 8 + (n & 7)] =
                        f2bf(fmaxf(a3[nt][r], 0.f));
                }
        }

        // ---- P5: h4 = relu(h3 @ w4^T) -> cols 64..191 (wave-local rows) ----
        {
            f32x4 a4[8];
            #pragma unroll
            for (int nt = 0; nt < 8; ++nt) a4[nt] = (f32x4){0.f, 0.f, 0.f, 0.f};
            #pragma unroll
            for (int ss = 0; ss < 2; ++ss) {
                int js = ss * 4 + q, r = w * 16 + l15;
                bf16x8 a = *(const bf16x8*)&pc[r * 192 + (16 | ((js ^ r) & 7)) * 8];
                #pragma unroll
                for (int nt = 0; nt < 8; ++nt) {
                    int rw = nt * 16 + l15;
                    bf16x8 b = *(const bf16x8*)&sw4[rw * 64 + ((js ^ rw) & 7) * 8];
                    a4[nt] = MFMA16(a, b, a4[nt]);
                }
            }
            #pragma unroll
            for (int nt = 0; nt < 8; ++nt)
                #pragma unroll
                for (int r = 0; r < 4; ++r) {
                    int m  = w * 16 + q * 4 + r;
                    int n4 = nt * 16 + l15;
                    int j  = 8 + (n4 >> 3);
                    int p  = (j & 24) | ((j ^ m) & 7);
                    pc[m * 192 + p * 8 + (n4 & 7)] = f2bf(fmaxf(a4[nt][r], 0.f));
                }
        }
        __syncthreads();   // h4 visible to all waves

        // ---- mlp5: A from LDS, B from VGPRs. 96 MFMA/wave ----
        {
            f32x4 acc[4][4];
            #pragma unroll
            for (int mt = 0; mt < 4; ++mt)
                #pragma unroll
                for (int nt = 0; nt < 4; ++nt) acc[mt][nt] = (f32x4){0.f, 0.f, 0.f, 0.f};
            #pragma unroll
            for (int s = 0; s < 6; ++s) {
                int j = s * 4 + q;
                bf16x8 a[4];
                #pragma unroll
                for (int mt = 0; mt < 4; ++mt) {
                    int r = mw * 64 + mt * 16 + l15;
                    int p = (j & 24) | ((j ^ r) & 7);
                    a[mt] = *(const bf16x8*)&pc[r * 192 + p * 8];
                }
                #pragma unroll
                for (int mt = 0; mt < 4; ++mt)
                    #pragma unroll
                    for (int nt = 0; nt < 4; ++nt)
                        acc[mt][nt] = MFMA16(a[mt], b5[s][nt], acc[mt][nt]);
            }
            #pragma unroll
            for (int nt = 0; nt < 4; ++nt)
                #pragma unroll
                for (int mt = 0; mt < 4; ++mt)
                    rmax[nt] = maxf4(rmax[nt], acc[mt][nt]);   // relu via 0-init
        }

        // ---- commit prefetched A(t+1) to the other buffer ----
        if (t < 31) {
            #pragma unroll
            for (int c = 0; c < 2; ++c) {
                int i = c * 512 + tid, r = i >> 3, js = i & 7;
                *(u16x8*)&pn[r * 192 + ((js ^ r) & 7) * 8]       = vg[c];
                *(u16x8*)&pn[r * 192 + (8 | ((js ^ r) & 7)) * 8] = vh[c];
            }
        }
        __syncthreads();
        u16* tmp = pc; pc = pn; pn = tmp;
    }

    // ---- column-max reduce + one atomic pass ----
    #pragma unroll
    for (int nt = 0; nt < 4; ++nt) {
        float mx = fmaxf(fmaxf(rmax[nt][0], rmax[nt][1]),
                         fmaxf(rmax[nt][2], rmax[nt][3]));
        mx = fmaxf(mx, __shfl_xor(mx, 16, 64));
        mx = fmaxf(mx, __shfl_xor(mx, 32, 64));
        if (q == 0)
            atomicMax(&gout[bcol0 + nt * 16 + l15], __float_as_int(mx));
    }
}

// ---------------------------------------------------------------------------
// k4: classifier head, pure f32. One wave per output row.
// ---------------------------------------------------------------------------
__global__ void k4_f1(const float* __restrict__ wf1)
{
    int r = blockIdx.x, l = threadIdx.x;
    float s = 0.f;
    #pragma unroll
    for (int i = 0; i < 16; ++i) s += wf1[r * 1024 + i * 64 + l] * g_buf[i * 64 + l];
    #pragma unroll
    for (int o = 32; o; o >>= 1) s += __shfl_down(s, o, 64);
    if (!l) f1_buf[r] = fmaxf(s, 0.f);
}
__global__ void k4_f2(const float* __restrict__ wf2)
{
    int r = blockIdx.x, l = threadIdx.x;
    float s = 0.f;
    #pragma unroll
    for (int i = 0; i < 8; ++i) s += wf2[r * 512 + i * 64 + l] * f1_buf[i * 64 + l];
    #pragma unroll
    for (int o = 32; o; o >>= 1) s += __shfl_down(s, o, 64);
    if (!l) f2_buf[r] = fmaxf(s, 0.f);
}
__global__ void k4_out(const float* __restrict__ wf3, float* __restrict__ out)
{
    int r = blockIdx.x, l = threadIdx.x;
    float s = 0.f;
    #pragma unroll
    for (int i = 0; i < 4; ++i) s += wf3[r * 256 + i * 64 + l] * f2_buf[i * 64 + l];
    #pragma unroll
    for (int o = 32; o; o >>= 1) s += __shfl_down(s, o, 64);
    if (!l) out[r] = s;
}

// ---------------------------------------------------------------------------
extern "C" void kernel_launch(void* const* d_in, const int* in_sizes, int n_in,
                              void* d_out, int out_size, void* d_ws, size_t ws_size,
                              hipStream_t stream)
{
    (void)in_sizes; (void)n_in; (void)out_size; (void)d_ws; (void)ws_size;
    const float* x   = (const float*)d_in[0];
    const int*   idx = (const int*)d_in[2];
    const float* w1  = (const float*)d_in[3];
    const float* w2  = (const float*)d_in[4];
    const float* w3  = (const float*)d_in[5];
    const float* w4  = (const float*)d_in[6];
    const float* w5  = (const float*)d_in[7];
    const float* wf1 = (const float*)d_in[8];
    const float* wf2 = (const float*)d_in[9];
    const float* wf3 = (const float*)d_in[10];

    float* gptr;
    hipGetSymbolAddress((void**)&gptr, HIP_SYMBOL(g_buf));

    k0_zero <<<1, 1024, 0, stream>>>();
    kcvt    <<<816, 256, 0, stream>>>(w3, w4, w5);
    k1_mlp  <<<262144 / 64, 256, 0, stream>>>(x, w1, w2);
    k2_pool <<<262144 * 8 / 256, 256, 0, stream>>>(idx);
    k3_fused<<<256, 512, 0, stream>>>((int*)gptr);
    k4_f1   <<<512, 64, 0, stream>>>(wf1);
    k4_f2   <<<256, 64, 0, stream>>>(wf2);
    k4_out  <<<40, 64, 0, stream>>>(wf3, (float*)d_out);
}

// Round 4
// 482.157 us; speedup vs baseline: 1.0031x; 1.0031x over previous
//
#include <hip/hip_runtime.h>
#include <hip/hip_bf16.h>
#include <stdint.h>

typedef unsigned short u16;
typedef __bf16 bf16x8 __attribute__((ext_vector_type(8)));
typedef float  f32x4  __attribute__((ext_vector_type(4)));
typedef u16    u16x8  __attribute__((ext_vector_type(8)));

__device__ __forceinline__ float bf2f(u16 u) {
    return __uint_as_float(((unsigned)u) << 16);
}
__device__ __forceinline__ u16 f2bf(float f) {   // round-to-nearest-even
    unsigned u = __float_as_uint(f);
    u += 0x7fffu + ((u >> 16) & 1u);
    return (u16)(u >> 16);
}
__device__ __forceinline__ u16x8 maxu16(u16x8 a, u16x8 b) {
    u16x8 r;
    #pragma unroll
    for (int e = 0; e < 8; ++e) r[e] = a[e] > b[e] ? a[e] : b[e];
    return r;
}
__device__ __forceinline__ f32x4 maxf4(f32x4 a, f32x4 b) {
    f32x4 r;
    #pragma unroll
    for (int e = 0; e < 4; ++e) r[e] = fmaxf(a[e], b[e]);
    return r;
}

#define MFMA16(a, b, c) __builtin_amdgcn_mfma_f32_16x16x32_bf16(a, b, c, 0, 0, 0)

// Static device buffers — no d_ws dependency.
__device__ u16   h2g_buf[262144 * 64];   // h2 [N][64] bf16 (33.5 MB)
__device__ u16   gm_buf [262144 * 64];   // neighbor-max [N][64] bf16 (33.5 MB)
__device__ u16   w3b[64 * 64];           // weights pre-converted to bf16
__device__ u16   w4b[128 * 64];
__device__ u16   w5b[1024 * 192];
__device__ float g_buf[1024];            // global column max (>= 0)
__device__ float f1_buf[512];
__device__ float f2_buf[256];

// ---------------------------------------------------------------------------
__global__ void k0_zero() { g_buf[threadIdx.x] = 0.f; }

__global__ void kcvt(const float* __restrict__ w3f, const float* __restrict__ w4f,
                     const float* __restrict__ w5f)
{
    int i = blockIdx.x * 256 + threadIdx.x;
    if (i < 4096)        w3b[i]         = f2bf(w3f[i]);
    else if (i < 12288)  w4b[i - 4096]  = f2bf(w4f[i - 4096]);
    else                 w5b[i - 12288] = f2bf(w5f[i - 12288]);
}

// ---------------------------------------------------------------------------
// k1: mlp1+mlp2 for 64 points/block (f32 in -> bf16). Writes h2g_buf.
// ---------------------------------------------------------------------------
__global__ __launch_bounds__(256) void k1_mlp(
    const float* __restrict__ xf, const float* __restrict__ w1f,
    const float* __restrict__ w2f)
{
    __shared__ __align__(16) u16 sw1[64 * 4];
    __shared__ __align__(16) u16 sx [64 * 4];
    __shared__ __align__(16) u16 sw2[64 * 72];
    __shared__ __align__(16) u16 shA[64 * 72];
    __shared__ __align__(16) u16 sh2[64 * 72];

    const int tid = threadIdx.x;
    const int p0  = blockIdx.x * 64;

    for (int i = tid; i < 64 * 64; i += 256)
        sw2[(i >> 6) * 72 + (i & 63)] = f2bf(w2f[i]);
    if (tid < 192) {
        sw1[(tid / 3) * 4 + tid % 3] = f2bf(w1f[tid]);
        sx [(tid / 3) * 4 + tid % 3] = f2bf(xf[p0 * 3 + tid]);
    }
    __syncthreads();

    {   // L1 via VALU (K=3)
        int m = tid & 63, ng = tid >> 6;
        float x0 = bf2f(sx[m * 4]), x1 = bf2f(sx[m * 4 + 1]), x2 = bf2f(sx[m * 4 + 2]);
        #pragma unroll
        for (int j = 0; j < 16; ++j) {
            int n = ng * 16 + j;
            float s = x0 * bf2f(sw1[n * 4]) + x1 * bf2f(sw1[n * 4 + 1]) + x2 * bf2f(sw1[n * 4 + 2]);
            shA[m * 72 + n] = f2bf(fmaxf(s, 0.f));
        }
    }
    __syncthreads();

    const int lane = tid & 63, w = tid >> 6, q = lane >> 4, l15 = lane & 15;
    const int mrow = 16 * w;

    f32x4 acc2[4];
    #pragma unroll
    for (int nt = 0; nt < 4; ++nt) acc2[nt] = (f32x4){0.f, 0.f, 0.f, 0.f};
    #pragma unroll
    for (int s = 0; s < 2; ++s) {
        bf16x8 a = *(const bf16x8*)&shA[(mrow + l15) * 72 + s * 32 + q * 8];
        #pragma unroll
        for (int nt = 0; nt < 4; ++nt) {
            bf16x8 b = *(const bf16x8*)&sw2[(nt * 16 + l15) * 72 + s * 32 + q * 8];
            acc2[nt] = MFMA16(a, b, acc2[nt]);
        }
    }
    #pragma unroll
    for (int nt = 0; nt < 4; ++nt)
        #pragma unroll
        for (int r = 0; r < 4; ++r) {
            int m = mrow + q * 4 + r;
            sh2[m * 72 + nt * 16 + l15] = f2bf(fmaxf(acc2[nt][r], 0.f));
        }
    __syncthreads();

    {
        int row = tid >> 2, c = (tid & 3) * 16;
        *(u16x8*)&h2g_buf[(size_t)p0 * 64 + tid * 16]     = *(const u16x8*)&sh2[row * 72 + c];
        *(u16x8*)&h2g_buf[(size_t)p0 * 64 + tid * 16 + 8] = *(const u16x8*)&sh2[row * 72 + c + 8];
    }
}

// ---------------------------------------------------------------------------
// k2_pool: 8 threads per point (thread owns a 16B channel chunk). 16
//   INDEPENDENT gather loads issued back-to-back per thread, local packed-u16
//   max (valid: post-relu bf16 >= 0), direct 16B store.
// ---------------------------------------------------------------------------
__global__ __launch_bounds__(256) void k2_pool(const int* __restrict__ idx)
{
    const size_t gt = (size_t)blockIdx.x * 256 + threadIdx.x;
    const size_t p  = gt >> 3;              // point
    const int    c  = (threadIdx.x & 7) * 8; // channel chunk

    u16x8 v[16];
    #pragma unroll
    for (int k = 0; k < 16; ++k) {
        int j = idx[p * 16 + k];
        v[k] = *(const u16x8*)&h2g_buf[(size_t)j * 64 + c];
    }
    u16x8 m = v[0];
    #pragma unroll
    for (int k = 1; k < 16; ++k) m = maxu16(m, v[k]);
    *(u16x8*)&gm_buf[p * 64 + c] = m;
}

// ---------------------------------------------------------------------------
// k3 v5: PERSISTENT blocks, B (w5) resident in VGPRs.
//   Structure identical to v3/v4.  The change: force the register budget via
//   __attribute__((amdgpu_waves_per_eu(2,2))).  Evidence from R2/R3:
//   launch_bounds' 2nd arg only CAPS the budget; with (512,2) AND (512,1) the
//   allocator targeted 4 waves/EU (VGPR_Count=128) and spilled the ~230 live
//   regs (b5=96 + acc=64 + rmax/a/prefetch/addr ~70) -> WRITE_SIZE 163MB of
//   scratch writeback, MfmaUtil 20%, 262us.  waves_per_eu(2,2) sets the
//   occupancy target the allocator actually obeys -> 256-VGPR budget, no
//   spill.  Occupancy is unchanged: LDS 120KB already limits to 1 block/CU
//   (8 waves = 2 waves/EU).
//   Grid = 256 blocks x 512 threads (8 waves: 2m x 4n).  Block owns a 256-col
//   group of w5 (cg = bid>>6) and loops over 32 row-tiles (brow = bid&63).
//   The 4 blocks sharing a row range have equal bid%8 -> same XCD -> A
//   fetched once per XCD L2 (FETCH 46MB confirms).
//   Per tile: prefetch A(t+1) to regs -> P4 (h3, wave-local rows) -> P5 (h4,
//   wave-local) -> barrier -> mlp5 (6 x [4 ds_read + 16 MFMA], B from regs)
//   -> write A(t+1) -> barrier.  Column-max in regs; atomics at block end.
// ---------------------------------------------------------------------------
__global__ __launch_bounds__(512)
__attribute__((amdgpu_waves_per_eu(2, 2)))
void k3_fused(int* __restrict__ gout)
{
    __shared__ __align__(16) u16 lds[61440];      // 120 KB
    u16* sA0 = lds;                               // [128][192] swizzled
    u16* sA1 = lds + 24576;
    u16* sw3 = lds + 49152;                       // [64][64] swizzled
    u16* sw4 = lds + 53248;                       // [128][64] swizzled

    const int tid  = threadIdx.x;
    const int lane = tid & 63, w = tid >> 6, q = lane >> 4, l15 = lane & 15;
    const int mw   = w & 1, nw = w >> 1;
    const int cg   = blockIdx.x >> 6;             // column group 0..3
    const int brow = blockIdx.x & 63;             // row chunk   0..63
    const int bcol0 = cg * 256 + nw * 64;

    // ---- stage w3/w4 into LDS (once) ----
    {
        int r = tid >> 3, js = tid & 7;
        *(u16x8*)&sw3[r * 64 + ((js ^ r) & 7) * 8] = *(const u16x8*)&w3b[r * 64 + js * 8];
        #pragma unroll
        for (int c = 0; c < 2; ++c) {
            int i = c * 512 + tid, r4 = i >> 3, j4 = i & 7;
            *(u16x8*)&sw4[r4 * 64 + ((j4 ^ r4) & 7) * 8] = *(const u16x8*)&w4b[r4 * 64 + j4 * 8];
        }
    }

    // ---- B (w5) fragments resident in VGPRs: 24 x bf16x8 = 96 VGPR ----
    bf16x8 b5[6][4];
    #pragma unroll
    for (int s = 0; s < 6; ++s)
        #pragma unroll
        for (int nt = 0; nt < 4; ++nt)
            b5[s][nt] = *(const bf16x8*)&w5b[(size_t)(bcol0 + nt * 16 + l15) * 192 + s * 32 + q * 8];

    // ---- stage tile 0 ----
    {
        size_t R0 = (size_t)brow * 32 * 128;
        #pragma unroll
        for (int c = 0; c < 2; ++c) {
            int i = c * 512 + tid, r = i >> 3, js = i & 7;
            *(u16x8*)&sA0[r * 192 + ((js ^ r) & 7) * 8] =
                *(const u16x8*)&gm_buf[(R0 + r) * 64 + js * 8];
            *(u16x8*)&sA0[r * 192 + (8 | ((js ^ r) & 7)) * 8] =
                *(const u16x8*)&h2g_buf[(R0 + r) * 64 + js * 8];
        }
    }
    __syncthreads();

    f32x4 rmax[4];
    #pragma unroll
    for (int nt = 0; nt < 4; ++nt) rmax[nt] = (f32x4){0.f, 0.f, 0.f, 0.f};

    u16* pc = sA0;
    u16* pn = sA1;

    #pragma unroll 1
    for (int t = 0; t < 32; ++t) {
        // ---- prefetch A(t+1) into regs (latency hidden under compute) ----
        u16x8 vg[2], vh[2];
        if (t < 31) {
            size_t R1 = (size_t)(brow * 32 + t + 1) * 128;
            #pragma unroll
            for (int c = 0; c < 2; ++c) {
                int i = c * 512 + tid, r = i >> 3, js = i & 7;
                vg[c] = *(const u16x8*)&gm_buf[(R1 + r) * 64 + js * 8];
                vh[c] = *(const u16x8*)&h2g_buf[(R1 + r) * 64 + js * 8];
            }
        }

        // ---- P4: h3 = relu(h2 @ w3^T) -> cols 128..191 (wave-local rows) ----
        {
            f32x4 a3[4];
            #pragma unroll
            for (int nt = 0; nt < 4; ++nt) a3[nt] = (f32x4){0.f, 0.f, 0.f, 0.f};
            #pragma unroll
            for (int ss = 0; ss < 2; ++ss) {
                int js = ss * 4 + q, r = w * 16 + l15;
                bf16x8 a = *(const bf16x8*)&pc[r * 192 + (8 | ((js ^ r) & 7)) * 8];
                #pragma unroll
                for (int nt = 0; nt < 4; ++nt) {
                    int rw = nt * 16 + l15;
                    bf16x8 b = *(const bf16x8*)&sw3[rw * 64 + ((js ^ rw) & 7) * 8];
                    a3[nt] = MFMA16(a, b, a3[nt]);
                }
            }
            #pragma unroll
            for (int nt = 0; nt < 4; ++nt)
                #pragma unroll
                for (int r = 0; r < 4; ++r) {
                    int m = w * 16 + q * 4 + r;
                    int n = nt * 16 + l15;
                    pc[m * 192 + (16 | (((n >> 3) ^ m) & 7)) * 8 + (n & 7)] =
                        f2bf(fmaxf(a3[nt][r], 0.f));
                }
        }

        // ---- P5: h4 = relu(h3 @ w4^T) -> cols 64..191 (wave-local rows) ----
        {
            f32x4 a4[8];
            #pragma unroll
            for (int nt = 0; nt < 8; ++nt) a4[nt] = (f32x4){0.f, 0.f, 0.f, 0.f};
            #pragma unroll
            for (int ss = 0; ss < 2; ++ss) {
                int js = ss * 4 + q, r = w * 16 + l15;
                bf16x8 a = *(const bf16x8*)&pc[r * 192 + (16 | ((js ^ r) & 7)) * 8];
                #pragma unroll
                for (int nt = 0; nt < 8; ++nt) {
                    int rw = nt * 16 + l15;
                    bf16x8 b = *(const bf16x8*)&sw4[rw * 64 + ((js ^ rw) & 7) * 8];
                    a4[nt] = MFMA16(a, b, a4[nt]);
                }
            }
            #pragma unroll
            for (int nt = 0; nt < 8; ++nt)
                #pragma unroll
                for (int r = 0; r < 4; ++r) {
                    int m  = w * 16 + q * 4 + r;
                    int n4 = nt * 16 + l15;
                    int j  = 8 + (n4 >> 3);
                    int p  = (j & 24) | ((j ^ m) & 7);
                    pc[m * 192 + p * 8 + (n4 & 7)] = f2bf(fmaxf(a4[nt][r], 0.f));
                }
        }
        __syncthreads();   // h4 visible to all waves

        // ---- mlp5: A from LDS, B from VGPRs. 96 MFMA/wave ----
        {
            f32x4 acc[4][4];
            #pragma unroll
            for (int mt = 0; mt < 4; ++mt)
                #pragma unroll
                for (int nt = 0; nt < 4; ++nt) acc[mt][nt] = (f32x4){0.f, 0.f, 0.f, 0.f};
            #pragma unroll
            for (int s = 0; s < 6; ++s) {
                int j = s * 4 + q;
                bf16x8 a[4];
                #pragma unroll
                for (int mt = 0; mt < 4; ++mt) {
                    int r = mw * 64 + mt * 16 + l15;
                    int p = (j & 24) | ((j ^ r) & 7);
                    a[mt] = *(const bf16x8*)&pc[r * 192 + p * 8];
                }
                #pragma unroll
                for (int mt = 0; mt < 4; ++mt)
                    #pragma unroll
                    for (int nt = 0; nt < 4; ++nt)
                        acc[mt][nt] = MFMA16(a[mt], b5[s][nt], acc[mt][nt]);
            }
            #pragma unroll
            for (int nt = 0; nt < 4; ++nt)
                #pragma unroll
                for (int mt = 0; mt < 4; ++mt)
                    rmax[nt] = maxf4(rmax[nt], acc[mt][nt]);   // relu via 0-init
        }

        // ---- commit prefetched A(t+1) to the other buffer ----
        if (t < 31) {
            #pragma unroll
            for (int c = 0; c < 2; ++c) {
                int i = c * 512 + tid, r = i >> 3, js = i & 7;
                *(u16x8*)&pn[r * 192 + ((js ^ r) & 7) * 8]       = vg[c];
                *(u16x8*)&pn[r * 192 + (8 | ((js ^ r) & 7)) * 8] = vh[c];
            }
        }
        __syncthreads();
        u16* tmp = pc; pc = pn; pn = tmp;
    }

    // ---- column-max reduce + one atomic pass ----
    #pragma unroll
    for (int nt = 0; nt < 4; ++nt) {
        float mx = fmaxf(fmaxf(rmax[nt][0], rmax[nt][1]),
                         fmaxf(rmax[nt][2], rmax[nt][3]));
        mx = fmaxf(mx, __shfl_xor(mx, 16, 64));
        mx = fmaxf(mx, __shfl_xor(mx, 32, 64));
        if (q == 0)
            atomicMax(&gout[bcol0 + nt * 16 + l15], __float_as_int(mx));
    }
}

// ---------------------------------------------------------------------------
// k4: classifier head, pure f32. One wave per output row.
// ---------------------------------------------------------------------------
__global__ void k4_f1(const float* __restrict__ wf1)
{
    int r = blockIdx.x, l = threadIdx.x;
    float s = 0.f;
    #pragma unroll
    for (int i = 0; i < 16; ++i) s += wf1[r * 1024 + i * 64 + l] * g_buf[i * 64 + l];
    #pragma unroll
    for (int o = 32; o; o >>= 1) s += __shfl_down(s, o, 64);
    if (!l) f1_buf[r] = fmaxf(s, 0.f);
}
__global__ void k4_f2(const float* __restrict__ wf2)
{
    int r = blockIdx.x, l = threadIdx.x;
    float s = 0.f;
    #pragma unroll
    for (int i = 0; i < 8; ++i) s += wf2[r * 512 + i * 64 + l] * f1_buf[i * 64 + l];
    #pragma unroll
    for (int o = 32; o; o >>= 1) s += __shfl_down(s, o, 64);
    if (!l) f2_buf[r] = fmaxf(s, 0.f);
}
__global__ void k4_out(const float* __restrict__ wf3, float* __restrict__ out)
{
    int r = blockIdx.x, l = threadIdx.x;
    float s = 0.f;
    #pragma unroll
    for (int i = 0; i < 4; ++i) s += wf3[r * 256 + i * 64 + l] * f2_buf[i * 64 + l];
    #pragma unroll
    for (int o = 32; o; o >>= 1) s += __shfl_down(s, o, 64);
    if (!l) out[r] = s;
}

// ---------------------------------------------------------------------------
extern "C" void kernel_launch(void* const* d_in, const int* in_sizes, int n_in,
                              void* d_out, int out_size, void* d_ws, size_t ws_size,
                              hipStream_t stream)
{
    (void)in_sizes; (void)n_in; (void)out_size; (void)d_ws; (void)ws_size;
    const float* x   = (const float*)d_in[0];
    const int*   idx = (const int*)d_in[2];
    const float* w1  = (const float*)d_in[3];
    const float* w2  = (const float*)d_in[4];
    const float* w3  = (const float*)d_in[5];
    const float* w4  = (const float*)d_in[6];
    const float* w5  = (const float*)d_in[7];
    const float* wf1 = (const float*)d_in[8];
    const float* wf2 = (const float*)d_in[9];
    const float* wf3 = (const float*)d_in[10];

    float* gptr;
    hipGetSymbolAddress((void**)&gptr, HIP_SYMBOL(g_buf));

    k0_zero <<<1, 1024, 0, stream>>>();
    kcvt    <<<816, 256, 0, stream>>>(w3, w4, w5);
    k1_mlp  <<<262144 / 64, 256, 0, stream>>>(x, w1, w2);
    k2_pool <<<262144 * 8 / 256, 256, 0, stream>>>(idx);
    k3_fused<<<256, 512, 0, stream>>>((int*)gptr);
    k4_f1   <<<512, 64, 0, stream>>>(wf1);
    k4_f2   <<<256, 64, 0, stream>>>(wf2);
    k4_out  <<<40, 64, 0, stream>>>(wf3, (float*)d_out);
}

// Round 5
// 417.330 us; speedup vs baseline: 1.1589x; 1.1553x over previous
//
#include <hip/hip_runtime.h>
#include <hip/hip_bf16.h>
#include <stdint.h>

typedef unsigned short u16;
typedef __bf16 bf16x8 __attribute__((ext_vector_type(8)));
typedef float  f32x4  __attribute__((ext_vector_type(4)));
typedef u16    u16x8  __attribute__((ext_vector_type(8)));

__device__ __forceinline__ float bf2f(u16 u) {
    return __uint_as_float(((unsigned)u) << 16);
}
__device__ __forceinline__ u16 f2bf(float f) {   // round-to-nearest-even
    unsigned u = __float_as_uint(f);
    u += 0x7fffu + ((u >> 16) & 1u);
    return (u16)(u >> 16);
}
__device__ __forceinline__ u16x8 maxu16(u16x8 a, u16x8 b) {
    u16x8 r;
    #pragma unroll
    for (int e = 0; e < 8; ++e) r[e] = a[e] > b[e] ? a[e] : b[e];
    return r;
}

#define MFMA16(a, b, c) __builtin_amdgcn_mfma_f32_16x16x32_bf16(a, b, c, 0, 0, 0)

// Static device buffers — no d_ws dependency.
__device__ u16   h2g_buf[262144 * 64];   // h2 [N][64] bf16 (33.5 MB)
__device__ u16   gm_buf [262144 * 64];   // neighbor-max [N][64] bf16 (33.5 MB)
__device__ u16   w3b[64 * 64];           // weights pre-converted to bf16
__device__ u16   w4b[128 * 64];
// w5 transposed to MFMA-fragment-contiguous layout:
//   w5t[((c16*6 + s)*64 + lane)*8 + e] = w5[c16*16 + (lane&15)][s*32 + (lane>>4)*8 + e]
// so a wave's B-frag load for (c16, s) is one fully-coalesced 1KB read.
__device__ u16   w5t[64 * 6 * 64 * 8];   // 384 KB, L2-resident per XCD
__device__ float g_buf[1024];            // global column max (>= 0)
__device__ float f1_buf[512];
__device__ float f2_buf[256];

// ---------------------------------------------------------------------------
__global__ void k0_zero() { g_buf[threadIdx.x] = 0.f; }

__global__ void kcvt(const float* __restrict__ w3f, const float* __restrict__ w4f,
                     const float* __restrict__ w5f)
{
    int i = blockIdx.x * 256 + threadIdx.x;     // 816*256 = 208896 = 4096+8192+196608
    if (i < 4096)        w3b[i]        = f2bf(w3f[i]);
    else if (i < 12288)  w4b[i - 4096] = f2bf(w4f[i - 4096]);
    else {
        int o    = i - 12288;                   // 0..196607
        int e    = o & 7;
        int lane = (o >> 3) & 63;
        int sg   = o >> 9;                      // c16*6 + s
        int s    = sg % 6, c16 = sg / 6;
        int q    = lane >> 4, l15 = lane & 15;
        w5t[o] = f2bf(w5f[(c16 * 16 + l15) * 192 + s * 32 + q * 8 + e]);
    }
}

// ---------------------------------------------------------------------------
// k1: mlp1+mlp2 for 64 points/block (f32 in -> bf16). Writes h2g_buf.
// ---------------------------------------------------------------------------
__global__ __launch_bounds__(256) void k1_mlp(
    const float* __restrict__ xf, const float* __restrict__ w1f,
    const float* __restrict__ w2f)
{
    __shared__ __align__(16) u16 sw1[64 * 4];
    __shared__ __align__(16) u16 sx [64 * 4];
    __shared__ __align__(16) u16 sw2[64 * 72];
    __shared__ __align__(16) u16 shA[64 * 72];
    __shared__ __align__(16) u16 sh2[64 * 72];

    const int tid = threadIdx.x;
    const int p0  = blockIdx.x * 64;

    for (int i = tid; i < 64 * 64; i += 256)
        sw2[(i >> 6) * 72 + (i & 63)] = f2bf(w2f[i]);
    if (tid < 192) {
        sw1[(tid / 3) * 4 + tid % 3] = f2bf(w1f[tid]);
        sx [(tid / 3) * 4 + tid % 3] = f2bf(xf[p0 * 3 + tid]);
    }
    __syncthreads();

    {   // L1 via VALU (K=3)
        int m = tid & 63, ng = tid >> 6;
        float x0 = bf2f(sx[m * 4]), x1 = bf2f(sx[m * 4 + 1]), x2 = bf2f(sx[m * 4 + 2]);
        #pragma unroll
        for (int j = 0; j < 16; ++j) {
            int n = ng * 16 + j;
            float s = x0 * bf2f(sw1[n * 4]) + x1 * bf2f(sw1[n * 4 + 1]) + x2 * bf2f(sw1[n * 4 + 2]);
            shA[m * 72 + n] = f2bf(fmaxf(s, 0.f));
        }
    }
    __syncthreads();

    const int lane = tid & 63, w = tid >> 6, q = lane >> 4, l15 = lane & 15;
    const int mrow = 16 * w;

    f32x4 acc2[4];
    #pragma unroll
    for (int nt = 0; nt < 4; ++nt) acc2[nt] = (f32x4){0.f, 0.f, 0.f, 0.f};
    #pragma unroll
    for (int s = 0; s < 2; ++s) {
        bf16x8 a = *(const bf16x8*)&shA[(mrow + l15) * 72 + s * 32 + q * 8];
        #pragma unroll
        for (int nt = 0; nt < 4; ++nt) {
            bf16x8 b = *(const bf16x8*)&sw2[(nt * 16 + l15) * 72 + s * 32 + q * 8];
            acc2[nt] = MFMA16(a, b, acc2[nt]);
        }
    }
    #pragma unroll
    for (int nt = 0; nt < 4; ++nt)
        #pragma unroll
        for (int r = 0; r < 4; ++r) {
            int m = mrow + q * 4 + r;
            sh2[m * 72 + nt * 16 + l15] = f2bf(fmaxf(acc2[nt][r], 0.f));
        }
    __syncthreads();

    {
        int row = tid >> 2, c = (tid & 3) * 16;
        *(u16x8*)&h2g_buf[(size_t)p0 * 64 + tid * 16]     = *(const u16x8*)&sh2[row * 72 + c];
        *(u16x8*)&h2g_buf[(size_t)p0 * 64 + tid * 16 + 8] = *(const u16x8*)&sh2[row * 72 + c + 8];
    }
}

// ---------------------------------------------------------------------------
// k2_pool: 8 threads per point (thread owns a 16B channel chunk). 16
//   INDEPENDENT gather loads issued back-to-back per thread, local packed-u16
//   max (valid: post-relu bf16 >= 0), direct 16B store.
// ---------------------------------------------------------------------------
__global__ __launch_bounds__(256) void k2_pool(const int* __restrict__ idx)
{
    const size_t gt = (size_t)blockIdx.x * 256 + threadIdx.x;
    const size_t p  = gt >> 3;              // point
    const int    c  = (threadIdx.x & 7) * 8; // channel chunk

    u16x8 v[16];
    #pragma unroll
    for (int k = 0; k < 16; ++k) {
        int j = idx[p * 16 + k];
        v[k] = *(const u16x8*)&h2g_buf[(size_t)j * 64 + c];
    }
    u16x8 m = v[0];
    #pragma unroll
    for (int k = 1; k < 16; ++k) m = maxu16(m, v[k]);
    *(u16x8*)&gm_buf[p * 64 + c] = m;
}

// ---------------------------------------------------------------------------
// k3 v6: lean-register, non-persistent.  Lesson from R1-R4: the allocator
//   pins this kernel at 128 VGPRs regardless of launch_bounds/waves_per_eu,
//   so the B-in-VGPR design (needs ~230) always spilled (163MB scratch
//   writes, MfmaUtil 20%).  v6 makes the live set fit ~120 regs:
//     - B read per-tile from w5t (L2-resident 384KB, frag-contiguous
//       coalesced 16B/lane loads) -> 16 transient regs instead of 96.
//     - acc reduced to scalar col-max BEFORE storing (4 regs, not 16).
//     - no persistence / no A double-buffer / no prefetch regs.
//   Grid 8192 = 2048 row-tiles x 4 col-groups; 512 thr (8 waves: 2m x 4n).
//   LDS 72KB (planes p0=gm, p1=h2->h4lo, p2=h3->h4hi, 16KB each + w3/w4
//   24KB) -> 2 blocks/CU, 16 waves/CU TLP hides L2 latency.
//   Swizzle per 64-col plane: chunk j of row r at pos ((j^r)&7)*8 (2-way
//   bank alias = free; measured 0 conflicts in prior rounds).
//   Flow: stage(gm,h2,w3,w4) -> bar -> P4 (h3, wave-local rows) -> P5 (h4,
//   wave-local) -> bar -> mlp5 (A from LDS, B from L2) -> reduce -> atomics.
// ---------------------------------------------------------------------------
__global__ __launch_bounds__(512) void k3_fused(int* __restrict__ gout)
{
    __shared__ __align__(16) u16 lds[36864];      // 72 KB
    u16* p0  = lds;                               // gm   [128][64]
    u16* p1  = lds + 8192;                        // h2 -> h4 lo
    u16* p2  = lds + 16384;                       // h3 -> h4 hi
    u16* sw3 = lds + 24576;                       // [64][64]
    u16* sw4 = lds + 28672;                       // [128][64]

    const int tid  = threadIdx.x;
    const int lane = tid & 63, w = tid >> 6, q = lane >> 4, l15 = lane & 15;
    const int mw   = w & 1, nw = w >> 1;
    const int cg   = blockIdx.x & 3;              // column group 0..3
    const size_t R0 = (size_t)(blockIdx.x >> 2) * 128;
    const int c16b = cg * 16 + nw * 4;            // wave's first 16-col tile of w5

    // ---- stage w3/w4 + A planes (gm, h2) ----
    {
        int r = tid >> 3, js = tid & 7;
        *(u16x8*)&sw3[r * 64 + ((js ^ r) & 7) * 8] = *(const u16x8*)&w3b[r * 64 + js * 8];
        #pragma unroll
        for (int c = 0; c < 2; ++c) {
            int i = c * 512 + tid, r4 = i >> 3, j4 = i & 7;
            *(u16x8*)&sw4[r4 * 64 + ((j4 ^ r4) & 7) * 8] = *(const u16x8*)&w4b[r4 * 64 + j4 * 8];
        }
        #pragma unroll
        for (int c = 0; c < 2; ++c) {
            int i = c * 512 + tid, ra = i >> 3, ja = i & 7;
            *(u16x8*)&p0[ra * 64 + ((ja ^ ra) & 7) * 8] =
                *(const u16x8*)&gm_buf[(R0 + ra) * 64 + ja * 8];
            *(u16x8*)&p1[ra * 64 + ((ja ^ ra) & 7) * 8] =
                *(const u16x8*)&h2g_buf[(R0 + ra) * 64 + ja * 8];
        }
    }
    __syncthreads();

    // ---- P4: h3 = relu(h2 @ w3^T) -> p2 (wave-local rows w*16..+15) ----
    {
        f32x4 a3[4];
        #pragma unroll
        for (int nt = 0; nt < 4; ++nt) a3[nt] = (f32x4){0.f, 0.f, 0.f, 0.f};
        #pragma unroll
        for (int ss = 0; ss < 2; ++ss) {
            int js = ss * 4 + q, r = w * 16 + l15;
            bf16x8 a = *(const bf16x8*)&p1[r * 64 + ((js ^ r) & 7) * 8];
            #pragma unroll
            for (int nt = 0; nt < 4; ++nt) {
                int rw = nt * 16 + l15;
                bf16x8 b = *(const bf16x8*)&sw3[rw * 64 + ((js ^ rw) & 7) * 8];
                a3[nt] = MFMA16(a, b, a3[nt]);
            }
        }
        #pragma unroll
        for (int nt = 0; nt < 4; ++nt)
            #pragma unroll
            for (int r = 0; r < 4; ++r) {
                int m = w * 16 + q * 4 + r;
                int n = nt * 16 + l15;
                p2[m * 64 + (((n >> 3) ^ m) & 7) * 8 + (n & 7)] =
                    f2bf(fmaxf(a3[nt][r], 0.f));
            }
    }
    // no barrier: P4 writes and P5 reads are wave-local rows

    // ---- P5: h4 = relu(h3 @ w4^T) -> p1 (cols 0..63), p2 (cols 64..127) ----
    {
        f32x4 a4[8];
        #pragma unroll
        for (int nt = 0; nt < 8; ++nt) a4[nt] = (f32x4){0.f, 0.f, 0.f, 0.f};
        #pragma unroll
        for (int ss = 0; ss < 2; ++ss) {
            int js = ss * 4 + q, r = w * 16 + l15;
            bf16x8 a = *(const bf16x8*)&p2[r * 64 + ((js ^ r) & 7) * 8];
            #pragma unroll
            for (int nt = 0; nt < 8; ++nt) {
                int rw = nt * 16 + l15;
                bf16x8 b = *(const bf16x8*)&sw4[rw * 64 + ((js ^ rw) & 7) * 8];
                a4[nt] = MFMA16(a, b, a4[nt]);
            }
        }
        #pragma unroll
        for (int nt = 0; nt < 8; ++nt)
            #pragma unroll
            for (int r = 0; r < 4; ++r) {
                int m  = w * 16 + q * 4 + r;
                int n4 = nt * 16 + l15;
                int j  = (n4 >> 3) & 7;
                u16* dp = (nt < 4) ? p1 : p2;
                dp[m * 64 + ((j ^ m) & 7) * 8 + (n4 & 7)] = f2bf(fmaxf(a4[nt][r], 0.f));
            }
    }
    __syncthreads();   // h4 visible to all waves

    // ---- mlp5: A from LDS planes, B streamed from L2 (w5t). 96 MFMA/wave ----
    {
        f32x4 acc[4][4];
        #pragma unroll
        for (int mt = 0; mt < 4; ++mt)
            #pragma unroll
            for (int nt = 0; nt < 4; ++nt) acc[mt][nt] = (f32x4){0.f, 0.f, 0.f, 0.f};
        #pragma unroll
        for (int s = 0; s < 6; ++s) {
            const u16* pa = (s < 2) ? p0 : ((s < 4) ? p1 : p2);
            int j = (s & 1) * 4 + q;
            bf16x8 b[4];
            #pragma unroll
            for (int nt = 0; nt < 4; ++nt)
                b[nt] = *(const bf16x8*)&w5t[(size_t)((c16b + nt) * 6 + s) * 512 + lane * 8];
            bf16x8 a[4];
            #pragma unroll
            for (int mt = 0; mt < 4; ++mt) {
                int r = mw * 64 + mt * 16 + l15;
                a[mt] = *(const bf16x8*)&pa[r * 64 + ((j ^ r) & 7) * 8];
            }
            #pragma unroll
            for (int mt = 0; mt < 4; ++mt)
                #pragma unroll
                for (int nt = 0; nt < 4; ++nt)
                    acc[mt][nt] = MFMA16(a[mt], b[nt], acc[mt][nt]);
        }

        // ---- column-max reduce + atomics (relu folded into 0-init) ----
        #pragma unroll
        for (int nt = 0; nt < 4; ++nt) {
            float mx = 0.f;
            #pragma unroll
            for (int mt = 0; mt < 4; ++mt)
                #pragma unroll
                for (int e = 0; e < 4; ++e) mx = fmaxf(mx, acc[mt][nt][e]);
            mx = fmaxf(mx, __shfl_xor(mx, 16, 64));
            mx = fmaxf(mx, __shfl_xor(mx, 32, 64));
            if (q == 0)
                atomicMax(&gout[cg * 256 + nw * 64 + nt * 16 + l15], __float_as_int(mx));
        }
    }
}

// ---------------------------------------------------------------------------
// k4: classifier head, pure f32. One wave per output row.
// ---------------------------------------------------------------------------
__global__ void k4_f1(const float* __restrict__ wf1)
{
    int r = blockIdx.x, l = threadIdx.x;
    float s = 0.f;
    #pragma unroll
    for (int i = 0; i < 16; ++i) s += wf1[r * 1024 + i * 64 + l] * g_buf[i * 64 + l];
    #pragma unroll
    for (int o = 32; o; o >>= 1) s += __shfl_down(s, o, 64);
    if (!l) f1_buf[r] = fmaxf(s, 0.f);
}
__global__ void k4_f2(const float* __restrict__ wf2)
{
    int r = blockIdx.x, l = threadIdx.x;
    float s = 0.f;
    #pragma unroll
    for (int i = 0; i < 8; ++i) s += wf2[r * 512 + i * 64 + l] * f1_buf[i * 64 + l];
    #pragma unroll
    for (int o = 32; o; o >>= 1) s += __shfl_down(s, o, 64);
    if (!l) f2_buf[r] = fmaxf(s, 0.f);
}
__global__ void k4_out(const float* __restrict__ wf3, float* __restrict__ out)
{
    int r = blockIdx.x, l = threadIdx.x;
    float s = 0.f;
    #pragma unroll
    for (int i = 0; i < 4; ++i) s += wf3[r * 256 + i * 64 + l] * f2_buf[i * 64 + l];
    #pragma unroll
    for (int o = 32; o; o >>= 1) s += __shfl_down(s, o, 64);
    if (!l) out[r] = s;
}

// ---------------------------------------------------------------------------
extern "C" void kernel_launch(void* const* d_in, const int* in_sizes, int n_in,
                              void* d_out, int out_size, void* d_ws, size_t ws_size,
                              hipStream_t stream)
{
    (void)in_sizes; (void)n_in; (void)out_size; (void)d_ws; (void)ws_size;
    const float* x   = (const float*)d_in[0];
    const int*   idx = (const int*)d_in[2];
    const float* w1  = (const float*)d_in[3];
    const float* w2  = (const float*)d_in[4];
    const float* w3  = (const float*)d_in[5];
    const float* w4  = (const float*)d_in[6];
    const float* w5  = (const float*)d_in[7];
    const float* wf1 = (const float*)d_in[8];
    const float* wf2 = (const float*)d_in[9];
    const float* wf3 = (const float*)d_in[10];

    float* gptr;
    hipGetSymbolAddress((void**)&gptr, HIP_SYMBOL(g_buf));

    k0_zero <<<1, 1024, 0, stream>>>();
    kcvt    <<<816, 256, 0, stream>>>(w3, w4, w5);
    k1_mlp  <<<262144 / 64, 256, 0, stream>>>(x, w1, w2);
    k2_pool <<<262144 * 8 / 256, 256, 0, stream>>>(idx);
    k3_fused<<<8192, 512, 0, stream>>>((int*)gptr);
    k4_f1   <<<512, 64, 0, stream>>>(wf1);
    k4_f2   <<<256, 64, 0, stream>>>(wf2);
    k4_out  <<<40, 64, 0, stream>>>(wf3, (float*)d_out);
}